// Round 1
// 148.089 us; speedup vs baseline: 1.0482x; 1.0482x over previous
//
#include <hip/hip_runtime.h>
#include <hip/hip_bf16.h>

#define B_  8
#define T_  16
#define N_  1024
#define FI  32
#define FO  64
#define K_  3

typedef float  f32x4  __attribute__((ext_vector_type(4)));
typedef short  bf16x8 __attribute__((ext_vector_type(8)));
typedef unsigned int   u32x4 __attribute__((ext_vector_type(4)));

__device__ inline unsigned short f2bf(float f) {
    unsigned int u = __float_as_uint(f);
    u += 0x7fffu + ((u >> 16) & 1u);
    return (unsigned short)(u >> 16);
}

// packed fp32x2 -> bf16x2 (v_cvt_pk_bf16_f32 on gfx950)
__device__ inline unsigned int pkbf2(float a, float b) {
    __hip_bfloat162 h = __float22bfloat162_rn(make_float2(a, b));
    union { __hip_bfloat162 h2; unsigned int u; } cvt;
    cvt.h2 = h;
    return cvt.u;
}

// async 16-B global -> LDS (global_load_lds_dwordx4); LDS dest is
// wave-uniform base + lane*16 (contiguous per wave).
__device__ inline void gl_lds16(const unsigned short* g, unsigned short* l) {
    __builtin_amdgcn_global_load_lds(
        (const __attribute__((address_space(1))) unsigned int*)g,
        (__attribute__((address_space(3))) unsigned int*)l, 16, 0, 0);
}

// ---------------------------------------------------------------------------
// Kernel 1 "prep" (unchanged, proven):
//   tasks 0..2047   : transpose x[b,t,j,f] fp32 -> xt[b, t*32+f, j] bf16
//   tasks 2048..6143: AC[b,k,ij] = cheb[k,ij]*att[b,ij] bf16 (b-parallel)
// ---------------------------------------------------------------------------
__global__ __launch_bounds__(256)
void prep(const float* __restrict__ x, const float* __restrict__ att,
          const float* __restrict__ cheb,
          unsigned short* __restrict__ xt, unsigned short* __restrict__ ac) {
    __shared__ __align__(16) float tile[64][33];
    int task = blockIdx.x;
    int tid  = threadIdx.x;

    if (task < 2048) {
        int jt = task & 15;
        int bt = task >> 4;
        int j0 = jt * 64;
        const float* src = x + (size_t)bt * (N_ * FI) + (size_t)j0 * FI;
        #pragma unroll
        for (int s = 0; s < 2; s++) {
            int e4 = tid + s * 256;
            int j  = e4 >> 3;
            int f4 = e4 & 7;
            f32x4 v = *(const f32x4*)(src + j * FI + f4 * 4);
            tile[j][f4 * 4 + 0] = v[0];
            tile[j][f4 * 4 + 1] = v[1];
            tile[j][f4 * 4 + 2] = v[2];
            tile[j][f4 * 4 + 3] = v[3];
        }
        __syncthreads();
        int f  = tid >> 3;
        int j8 = (tid & 7) * 8;
        u32x4 pk;
        #pragma unroll
        for (int u = 0; u < 4; u++)
            pk[u] = pkbf2(tile[j8 + 2 * u][f], tile[j8 + 2 * u + 1][f]);
        *(u32x4*)(xt + (size_t)bt * (32 * 1024) + j0 + f * 1024 + j8) = pk;
    } else {
        int e  = (task - 2048) * 256 + tid;   // 0..1048575
        int b  = e >> 17;
        size_t ij = (size_t)(e & 131071) * 8;
        const float* ap = att + (size_t)b * (N_ * N_) + ij;
        f32x4 a0 = ((const f32x4*)ap)[0];
        f32x4 a1 = ((const f32x4*)ap)[1];
        #pragma unroll
        for (int k = 0; k < K_; k++) {
            const float* cp = cheb + (size_t)k * (N_ * N_) + ij;
            f32x4 c0 = ((const f32x4*)cp)[0];
            f32x4 c1 = ((const f32x4*)cp)[1];
            u32x4 pk;
            pk[0] = pkbf2(c0[0] * a0[0], c0[1] * a0[1]);
            pk[1] = pkbf2(c0[2] * a0[2], c0[3] * a0[3]);
            pk[2] = pkbf2(c1[0] * a1[0], c1[1] * a1[1]);
            pk[3] = pkbf2(c1[2] * a1[2], c1[3] * a1[3]);
            *(u32x4*)(ac + (size_t)(b * K_ + k) * (N_ * N_) + ij) = pk;
        }
    }
}

// ---------------------------------------------------------------------------
// Kernel 2 (fused stage1+stage2): per block, 64(i) x 128(c) output tile for
// ALL K=3 orders at once (B-tile staged ONCE per K-step, shared across k:
// 24 MFMA per 11 ds_read vs old 16 per 8).  Then Theta applied in-block:
// acc -> bf16 -> Cs[t][i][q] (LD=104 pad), one 96-deep MFMA pass vs LDS
// Theta^T, relu, store out.  rhs intermediate eliminated entirely.
// Grid 512 = 2 blocks/CU (LDS 66.5 KB); b = XCD so xt[b] (1 MB) is L2-hot.
// ---------------------------------------------------------------------------
#define TS_LD 104
#define CS_LD 104

__global__ __launch_bounds__(256, 2)
void fused_gemm(const unsigned short* __restrict__ ac,
                const unsigned short* __restrict__ xt,
                const float* __restrict__ theta,
                float* __restrict__ out) {
    // union: main-loop staging (As 3*2048 + Bs 4096 = 10240) overlaid by
    // epilogue Cs (4*64*CS_LD = 26624 elems, 53.2 KB)
    __shared__ __align__(16) unsigned short ldsU[4 * 64 * CS_LD];
    __shared__ __align__(16) unsigned short Ts[FO * TS_LD];     // Theta^T, 13.3 KB

    unsigned short* As = ldsU;              // [k][64 rows i][32 j]
    unsigned short* Bs = ldsU + 3 * 2048;   // [128 rows c][32 j]
    unsigned short* Cs = ldsU;              // [4 t][64 i][CS_LD q]

    int blk  = blockIdx.x;
    int b    = blk & 7;          // XCD-aligned batch
    int slot = blk >> 3;         // 0..63
    int it   = slot >> 2;        // 0..15
    int ct   = slot & 3;         // 0..3
    int i0   = it * 64;
    int c0   = ct * 128;

    int tid  = threadIdx.x;
    int lane = tid & 63;
    int w    = tid >> 6;         // wave 0..3: owns i-rows w*16..w*16+15
    int quad = lane >> 4;
    int l15  = lane & 15;

    // stage Theta^T: Ts[o][q] = bf16(theta[q*64+o]), q = k*32+f
    #pragma unroll
    for (int s = 0; s < 24; s++) {
        int e = tid + s * 256;
        int q = e >> 6, o = e & 63;
        Ts[o * TS_LD + q] = f2bf(theta[e]);
    }

    const unsigned short* Ag = ac + (size_t)b * (K_ * N_ * N_);
    const unsigned short* Bg = xt + (size_t)b * (512 * 1024);

    int sr = tid >> 2;          // 0..63
    int sc = (tid & 3) * 8;     // 0/8/16/24

    const unsigned short* Arow = Ag + (size_t)(i0 + sr) * N_ + sc;
    const unsigned short* Brow = Bg + (size_t)(c0 + sr) * N_ + sc;
    unsigned short* Al = As + tid * 8;
    unsigned short* Bl = Bs + tid * 8;

    f32x4 acc[3][8];
    #pragma unroll
    for (int k = 0; k < 3; k++)
        #pragma unroll
        for (int nt = 0; nt < 8; nt++)
            acc[k][nt] = (f32x4){0.f, 0.f, 0.f, 0.f};

    for (int kb = 0; kb < 32; kb++) {
        int j0 = kb * 32;
        __syncthreads();
        #pragma unroll
        for (int k = 0; k < 3; k++)
            gl_lds16(Arow + (size_t)k * (N_ * N_) + j0, Al + k * 2048);
        gl_lds16(Brow + j0,           Bl);
        gl_lds16(Brow + 64 * N_ + j0, Bl + 64 * 32);
        __syncthreads();

        bf16x8 af[3], bfr[8];
        #pragma unroll
        for (int k = 0; k < 3; k++)
            af[k] = *(const bf16x8*)(As + k * 2048 + (w * 16 + l15) * 32 + quad * 8);
        #pragma unroll
        for (int nt = 0; nt < 8; nt++)
            bfr[nt] = *(const bf16x8*)(Bs + (nt * 16 + l15) * 32 + quad * 8);
        #pragma unroll
        for (int k = 0; k < 3; k++)
            #pragma unroll
            for (int nt = 0; nt < 8; nt++)
                acc[k][nt] = __builtin_amdgcn_mfma_f32_16x16x32_bf16(
                    af[k], bfr[nt], acc[k][nt], 0, 0, 0);
    }

    // ---- epilogue: acc -> bf16 Cs[t][i][q] ----
    // C/D layout: col(c) = nt*16+l15, row(i) = w*16 + quad*4 + reg
    // t_loc = nt>>1 (l15 < 16 so it never crosses), f = (nt&1)*16 + l15
    __syncthreads();              // all waves done reading As/Bs
    #pragma unroll
    for (int k = 0; k < 3; k++) {
        #pragma unroll
        for (int nt = 0; nt < 8; nt++) {
            int tl = nt >> 1;
            int q  = k * 32 + (nt & 1) * 16 + l15;
            #pragma unroll
            for (int reg = 0; reg < 4; reg++) {
                int il = w * 16 + quad * 4 + reg;
                Cs[(tl * 64 + il) * CS_LD + q] = f2bf(acc[k][nt][reg]);
            }
        }
    }
    __syncthreads();

    // ---- second GEMM: out[i][o] += Cs[t][i][q] * ThetaT[o][q], relu ----
    bf16x8 bq[4][3];
    #pragma unroll
    for (int nt2 = 0; nt2 < 4; nt2++)
        #pragma unroll
        for (int kc = 0; kc < 3; kc++)
            bq[nt2][kc] = *(const bf16x8*)(Ts + (nt2 * 16 + l15) * TS_LD + kc * 32 + quad * 8);

    #pragma unroll
    for (int tl = 0; tl < 4; tl++) {
        bf16x8 af2[3];
        #pragma unroll
        for (int kc = 0; kc < 3; kc++)
            af2[kc] = *(const bf16x8*)(Cs + (size_t)(tl * 64 + w * 16 + l15) * CS_LD + kc * 32 + quad * 8);
        f32x4 acc2[4];
        #pragma unroll
        for (int nt2 = 0; nt2 < 4; nt2++)
            acc2[nt2] = (f32x4){0.f, 0.f, 0.f, 0.f};
        #pragma unroll
        for (int kc = 0; kc < 3; kc++)
            #pragma unroll
            for (int nt2 = 0; nt2 < 4; nt2++)
                acc2[nt2] = __builtin_amdgcn_mfma_f32_16x16x32_bf16(
                    af2[kc], bq[nt2][kc], acc2[nt2], 0, 0, 0);

        int tg = ct * 4 + tl;
        #pragma unroll
        for (int nt2 = 0; nt2 < 4; nt2++) {
            int o = nt2 * 16 + l15;
            #pragma unroll
            for (int reg = 0; reg < 4; reg++) {
                size_t row = (size_t)(b * T_ + tg) * N_ + i0 + w * 16 + quad * 4 + reg;
                out[row * 64 + o] = fmaxf(acc2[nt2][reg], 0.f);
            }
        }
    }
}

// ---------------------------------------------------------------------------
extern "C" void kernel_launch(void* const* d_in, const int* in_sizes, int n_in,
                              void* d_out, int out_size, void* d_ws, size_t ws_size,
                              hipStream_t stream) {
    const float* x     = (const float*)d_in[0];   // [B,T,N,FI]
    const float* att   = (const float*)d_in[1];   // [B,N,N]
    const float* cheb  = (const float*)d_in[2];   // [K,N,N]
    const float* theta = (const float*)d_in[3];   // [K,FI,FO]
    float* out = (float*)d_out;                   // [B,T,N,FO]

    // workspace: xt bf16 8.4 MB | ac bf16 50.3 MB   (rhs eliminated)
    unsigned short* xt = (unsigned short*)d_ws;
    unsigned short* ac = xt + (size_t)B_ * 512 * 1024;

    prep<<<2048 + 4096, 256, 0, stream>>>(x, att, cheb, xt, ac);
    fused_gemm<<<512, 256, 0, stream>>>(ac, xt, theta, out);
}

// Round 2
// 147.967 us; speedup vs baseline: 1.0490x; 1.0008x over previous
//
#include <hip/hip_runtime.h>
#include <hip/hip_bf16.h>

#define B_  8
#define T_  16
#define N_  1024
#define FI  32
#define FO  64
#define K_  3

typedef float  f32x4  __attribute__((ext_vector_type(4)));
typedef short  bf16x8 __attribute__((ext_vector_type(8)));
typedef unsigned int   u32x4 __attribute__((ext_vector_type(4)));

__device__ inline unsigned short f2bf(float f) {
    unsigned int u = __float_as_uint(f);
    u += 0x7fffu + ((u >> 16) & 1u);
    return (unsigned short)(u >> 16);
}

// packed fp32x2 -> bf16x2 (v_cvt_pk_bf16_f32 on gfx950)
__device__ inline unsigned int pkbf2(float a, float b) {
    __hip_bfloat162 h = __float22bfloat162_rn(make_float2(a, b));
    union { __hip_bfloat162 h2; unsigned int u; } cvt;
    cvt.h2 = h;
    return cvt.u;
}

// async 16-B global -> LDS (global_load_lds_dwordx4); LDS dest is
// wave-uniform base + lane*16 (contiguous per wave).
__device__ inline void gl_lds16(const unsigned short* g, unsigned short* l) {
    __builtin_amdgcn_global_load_lds(
        (const __attribute__((address_space(1))) unsigned int*)g,
        (__attribute__((address_space(3))) unsigned int*)l, 16, 0, 0);
}

// ---------------------------------------------------------------------------
// Kernel 1 "prep" (unchanged, proven):
//   tasks 0..2047   : transpose x[b,t,j,f] fp32 -> xt[b, t*32+f, j] bf16
//   tasks 2048..6143: AC[b,k,ij] = cheb[k,ij]*att[b,ij] bf16 (b-parallel)
// ---------------------------------------------------------------------------
__global__ __launch_bounds__(256)
void prep(const float* __restrict__ x, const float* __restrict__ att,
          const float* __restrict__ cheb,
          unsigned short* __restrict__ xt, unsigned short* __restrict__ ac) {
    __shared__ __align__(16) float tile[64][33];
    int task = blockIdx.x;
    int tid  = threadIdx.x;

    if (task < 2048) {
        int jt = task & 15;
        int bt = task >> 4;
        int j0 = jt * 64;
        const float* src = x + (size_t)bt * (N_ * FI) + (size_t)j0 * FI;
        #pragma unroll
        for (int s = 0; s < 2; s++) {
            int e4 = tid + s * 256;
            int j  = e4 >> 3;
            int f4 = e4 & 7;
            f32x4 v = *(const f32x4*)(src + j * FI + f4 * 4);
            tile[j][f4 * 4 + 0] = v[0];
            tile[j][f4 * 4 + 1] = v[1];
            tile[j][f4 * 4 + 2] = v[2];
            tile[j][f4 * 4 + 3] = v[3];
        }
        __syncthreads();
        int f  = tid >> 3;
        int j8 = (tid & 7) * 8;
        u32x4 pk;
        #pragma unroll
        for (int u = 0; u < 4; u++)
            pk[u] = pkbf2(tile[j8 + 2 * u][f], tile[j8 + 2 * u + 1][f]);
        *(u32x4*)(xt + (size_t)bt * (32 * 1024) + j0 + f * 1024 + j8) = pk;
    } else {
        int e  = (task - 2048) * 256 + tid;   // 0..1048575
        int b  = e >> 17;
        size_t ij = (size_t)(e & 131071) * 8;
        const float* ap = att + (size_t)b * (N_ * N_) + ij;
        f32x4 a0 = ((const f32x4*)ap)[0];
        f32x4 a1 = ((const f32x4*)ap)[1];
        #pragma unroll
        for (int k = 0; k < K_; k++) {
            const float* cp = cheb + (size_t)k * (N_ * N_) + ij;
            f32x4 c0 = ((const f32x4*)cp)[0];
            f32x4 c1 = ((const f32x4*)cp)[1];
            u32x4 pk;
            pk[0] = pkbf2(c0[0] * a0[0], c0[1] * a0[1]);
            pk[1] = pkbf2(c0[2] * a0[2], c0[3] * a0[3]);
            pk[2] = pkbf2(c1[0] * a1[0], c1[1] * a1[1]);
            pk[3] = pkbf2(c1[2] * a1[2], c1[3] * a1[3]);
            *(u32x4*)(ac + (size_t)(b * K_ + k) * (N_ * N_) + ij) = pk;
        }
    }
}

// ---------------------------------------------------------------------------
// Kernel 2 (fused, v2): 64(i) x 128(c) tile, all K=3 at once, then Theta
// applied in-block.  This round:
//  (a) 2-phase double-buffered staging (T3-minimum): issue STAGE(kb+1) into
//      buf^1 BEFORE consuming buf — ONE barrier per K-step; the vmcnt(0)
//      drain at the barrier lands after ~900cy of ds_read+MFMA wall time.
//  (b) 16-B-slot XOR swizzle (T2, rule #21 form): LDS linear (gl_lds dest
//      must be), global SOURCE col pre-permuted slot^=(row>>1)&3, ds_read
//      applies the same XOR -> 8 distinct bank-starts / 16-lane group
//      (2-way = free) instead of 8-way conflict.
// LDS unchanged at 66.5 KB (2x10240-short staging unioned under 53KB Cs).
// ---------------------------------------------------------------------------
#define TS_LD 104
#define CS_LD 104
#define SBUF  10240   /* shorts per staging buffer: As 3*2048 + Bs 4096 */

__global__ __launch_bounds__(256, 2)
void fused_gemm(const unsigned short* __restrict__ ac,
                const unsigned short* __restrict__ xt,
                const float* __restrict__ theta,
                float* __restrict__ out) {
    // union: 2x staging (20480 shorts) overlaid by epilogue Cs (26624 shorts)
    __shared__ __align__(16) unsigned short ldsU[4 * 64 * CS_LD];
    __shared__ __align__(16) unsigned short Ts[FO * TS_LD];     // Theta^T

    unsigned short* Cs = ldsU;              // [4 t][64 i][CS_LD q]

    int blk  = blockIdx.x;
    int b    = blk & 7;          // XCD-aligned batch
    int slot = blk >> 3;         // 0..63
    int it   = slot >> 2;        // 0..15
    int ct   = slot & 3;         // 0..3
    int i0   = it * 64;
    int c0   = ct * 128;

    int tid  = threadIdx.x;
    int lane = tid & 63;
    int w    = tid >> 6;         // wave 0..3: owns i-rows w*16..w*16+15
    int quad = lane >> 4;
    int l15  = lane & 15;

    // stage Theta^T: Ts[o][q] = bf16(theta[q*64+o]), q = k*32+f
    #pragma unroll
    for (int s = 0; s < 24; s++) {
        int e = tid + s * 256;
        int q = e >> 6, o = e & 63;
        Ts[o * TS_LD + q] = f2bf(theta[e]);
    }

    const unsigned short* Ag = ac + (size_t)b * (K_ * N_ * N_);
    const unsigned short* Bg = xt + (size_t)b * (512 * 1024);

    int sr  = tid >> 2;                               // staged row 0..63
    int scs = (((tid & 3) ^ ((sr >> 1) & 3)) * 8);    // swizzled source col
    // note: row sr+64 has same (row>>1)&3 swizzle (64>>1 ≡ 0 mod 4)

    const unsigned short* Arow = Ag + (size_t)(i0 + sr) * N_ + scs;
    const unsigned short* Brow = Bg + (size_t)(c0 + sr) * N_ + scs;

    // read-side swizzle: global slot `quad` lives at LDS slot quad^s4
    int s4 = (l15 >> 1) & 3;
    int rdA = (w * 16 + l15) * 32 + ((quad ^ s4) * 8);
    int rdB0 = l15 * 32 + ((quad ^ s4) * 8);

    f32x4 acc[3][8];
    #pragma unroll
    for (int k = 0; k < 3; k++)
        #pragma unroll
        for (int nt = 0; nt < 8; nt++)
            acc[k][nt] = (f32x4){0.f, 0.f, 0.f, 0.f};

    // ---- 2-phase double-buffered K-loop ----
    {
        unsigned short* S0 = ldsU;
        int j0 = 0;
        #pragma unroll
        for (int k = 0; k < 3; k++)
            gl_lds16(Arow + (size_t)k * (N_ * N_) + j0, S0 + k * 2048 + tid * 8);
        gl_lds16(Brow + j0,            S0 + 6144 + tid * 8);
        gl_lds16(Brow + 64 * N_ + j0,  S0 + 6144 + 64 * 32 + tid * 8);
    }
    __syncthreads();   // prologue drain

    int cur = 0;
    for (int kb = 0; kb < 32; kb++) {
        unsigned short* Sc = ldsU + cur * SBUF;
        if (kb < 31) {
            unsigned short* Sn = ldsU + (cur ^ 1) * SBUF;
            int j1 = (kb + 1) * 32;
            #pragma unroll
            for (int k = 0; k < 3; k++)
                gl_lds16(Arow + (size_t)k * (N_ * N_) + j1, Sn + k * 2048 + tid * 8);
            gl_lds16(Brow + j1,            Sn + 6144 + tid * 8);
            gl_lds16(Brow + 64 * N_ + j1,  Sn + 6144 + 64 * 32 + tid * 8);
        }

        bf16x8 af[3], bfr[8];
        #pragma unroll
        for (int k = 0; k < 3; k++)
            af[k] = *(const bf16x8*)(Sc + k * 2048 + rdA);
        #pragma unroll
        for (int nt = 0; nt < 8; nt++)
            bfr[nt] = *(const bf16x8*)(Sc + 6144 + nt * 16 * 32 + rdB0);
        #pragma unroll
        for (int k = 0; k < 3; k++)
            #pragma unroll
            for (int nt = 0; nt < 8; nt++)
                acc[k][nt] = __builtin_amdgcn_mfma_f32_16x16x32_bf16(
                    af[k], bfr[nt], acc[k][nt], 0, 0, 0);

        __syncthreads();   // drains this iter's stage (had MFMA-time to land)
        cur ^= 1;
    }

    // ---- epilogue: acc -> bf16 Cs[t][i][q] ----
    // C/D layout: col(c) = nt*16+l15, row(i) = w*16 + quad*4 + reg
    // t_loc = nt>>1 (l15 < 16 so it never crosses), f = (nt&1)*16 + l15
    #pragma unroll
    for (int k = 0; k < 3; k++) {
        #pragma unroll
        for (int nt = 0; nt < 8; nt++) {
            int tl = nt >> 1;
            int q  = k * 32 + (nt & 1) * 16 + l15;
            #pragma unroll
            for (int reg = 0; reg < 4; reg++) {
                int il = w * 16 + quad * 4 + reg;
                Cs[(tl * 64 + il) * CS_LD + q] = f2bf(acc[k][nt][reg]);
            }
        }
    }
    __syncthreads();

    // ---- second GEMM: out[i][o] = relu( Cs[t][i][q] * ThetaT[o][q] ) ----
    bf16x8 bq[4][3];
    #pragma unroll
    for (int nt2 = 0; nt2 < 4; nt2++)
        #pragma unroll
        for (int kc = 0; kc < 3; kc++)
            bq[nt2][kc] = *(const bf16x8*)(Ts + (nt2 * 16 + l15) * TS_LD + kc * 32 + quad * 8);

    #pragma unroll
    for (int tl = 0; tl < 4; tl++) {
        bf16x8 af2[3];
        #pragma unroll
        for (int kc = 0; kc < 3; kc++)
            af2[kc] = *(const bf16x8*)(Cs + (size_t)(tl * 64 + w * 16 + l15) * CS_LD + kc * 32 + quad * 8);
        f32x4 acc2[4];
        #pragma unroll
        for (int nt2 = 0; nt2 < 4; nt2++)
            acc2[nt2] = (f32x4){0.f, 0.f, 0.f, 0.f};
        #pragma unroll
        for (int kc = 0; kc < 3; kc++)
            #pragma unroll
            for (int nt2 = 0; nt2 < 4; nt2++)
                acc2[nt2] = __builtin_amdgcn_mfma_f32_16x16x32_bf16(
                    af2[kc], bq[nt2][kc], acc2[nt2], 0, 0, 0);

        int tg = ct * 4 + tl;
        #pragma unroll
        for (int nt2 = 0; nt2 < 4; nt2++) {
            int o = nt2 * 16 + l15;
            #pragma unroll
            for (int reg = 0; reg < 4; reg++) {
                size_t row = (size_t)(b * T_ + tg) * N_ + i0 + w * 16 + quad * 4 + reg;
                out[row * 64 + o] = fmaxf(acc2[nt2][reg], 0.f);
            }
        }
    }
}

// ---------------------------------------------------------------------------
extern "C" void kernel_launch(void* const* d_in, const int* in_sizes, int n_in,
                              void* d_out, int out_size, void* d_ws, size_t ws_size,
                              hipStream_t stream) {
    const float* x     = (const float*)d_in[0];   // [B,T,N,FI]
    const float* att   = (const float*)d_in[1];   // [B,N,N]
    const float* cheb  = (const float*)d_in[2];   // [K,N,N]
    const float* theta = (const float*)d_in[3];   // [K,FI,FO]
    float* out = (float*)d_out;                   // [B,T,N,FO]

    // workspace: xt bf16 8.4 MB | ac bf16 50.3 MB   (rhs eliminated)
    unsigned short* xt = (unsigned short*)d_ws;
    unsigned short* ac = xt + (size_t)B_ * 512 * 1024;

    prep<<<2048 + 4096, 256, 0, stream>>>(x, att, cheb, xt, ac);
    fused_gemm<<<512, 256, 0, stream>>>(ac, xt, theta, out);
}